// Round 1
// baseline (2932.634 us; speedup 1.0000x reference)
//
#include <hip/hip_runtime.h>
#include <math.h>

#define H 768

__device__ __forceinline__ float gelu_exact(float x){
  return 0.5f * x * (1.0f + erff(x * 0.70710678118654752f));
}

// order-preserving float<->uint encoding for atomicMax on floats
__device__ __forceinline__ unsigned enc_f(float f){
  unsigned u = __float_as_uint(f);
  return (u & 0x80000000u) ? ~u : (u | 0x80000000u);
}
__device__ __forceinline__ float dec_f(unsigned v){
  unsigned u = (v & 0x80000000u) ? (v ^ 0x80000000u) : ~v;
  return __uint_as_float(u);
}

// ---------------- LayerNorm + exact GELU: one block (256 thr) per row ----------------
__global__ __launch_bounds__(256) void ln_gelu_kernel(
    const float* __restrict__ in, const float* __restrict__ g,
    const float* __restrict__ b, float* __restrict__ out, int rows){
  int row = blockIdx.x;
  if (row >= rows) return;
  int tid = threadIdx.x;
  const float* rp = in + (size_t)row * H;
  float v0 = rp[tid], v1 = rp[tid + 256], v2 = rp[tid + 512];
  __shared__ float red[4];
  int lane = tid & 63, wid = tid >> 6;
  float s = v0 + v1 + v2;
  for (int o = 32; o; o >>= 1) s += __shfl_down(s, o);
  if (lane == 0) red[wid] = s;
  __syncthreads();
  float mean = (red[0] + red[1] + red[2] + red[3]) * (1.0f / H);
  __syncthreads();
  float d0 = v0 - mean, d1 = v1 - mean, d2 = v2 - mean;
  s = d0*d0 + d1*d1 + d2*d2;
  for (int o = 32; o; o >>= 1) s += __shfl_down(s, o);
  if (lane == 0) red[wid] = s;
  __syncthreads();
  float var = (red[0] + red[1] + red[2] + red[3]) * (1.0f / H);
  float rstd = rsqrtf(var + 1e-5f);
  float* op = out + (size_t)row * H;
  float y0 = d0 * rstd * g[tid]       + b[tid];
  float y1 = d1 * rstd * g[tid + 256] + b[tid + 256];
  float y2 = d2 * rstd * g[tid + 512] + b[tid + 512];
  op[tid]       = gelu_exact(y0);
  op[tid + 256] = gelu_exact(y1);
  op[tid + 512] = gelu_exact(y2);
}

// ---------------- f32 GEMM: out[M,768] = A[M,768] @ W[768,768] + bias ----------------
// BM=BN=64, BK=16, 256 threads, 4x4 micro-tile per thread.
__global__ __launch_bounds__(256) void gemm_bias_kernel(
    const float* __restrict__ A, const float* __restrict__ W,
    const float* __restrict__ bias, float* __restrict__ out, int M){
  const int K = 768, NN = 768;
  __shared__ float As[16][64];
  __shared__ float Bs[16][64];
  int bn = blockIdx.x * 64;
  int bm = blockIdx.y * 64;
  int tid = threadIdx.x;
  int tx = tid & 15, ty = tid >> 4;
  float acc[4][4] = {{0.f}};
  int a_row = tid >> 2, a_c4 = (tid & 3) * 4;
  int b_row = tid >> 4, b_c4 = (tid & 15) * 4;
  const bool a_ok = (bm + a_row) < M;
  const float* aptr = A + (size_t)(bm + a_row) * K + a_c4;
  const float* bptr = W + (size_t)b_row * NN + bn + b_c4;
  for (int k0 = 0; k0 < K; k0 += 16){
    float4 av = a_ok ? *(const float4*)(aptr + k0) : make_float4(0.f,0.f,0.f,0.f);
    float4 bv = *(const float4*)(bptr + (size_t)k0 * NN);
    __syncthreads();
    As[a_c4 + 0][a_row] = av.x;
    As[a_c4 + 1][a_row] = av.y;
    As[a_c4 + 2][a_row] = av.z;
    As[a_c4 + 3][a_row] = av.w;
    *(float4*)&Bs[b_row][b_c4] = bv;
    __syncthreads();
#pragma unroll
    for (int kk = 0; kk < 16; kk++){
      float4 ra = *(const float4*)&As[kk][ty * 4];
      float4 rb = *(const float4*)&Bs[kk][tx * 4];
      acc[0][0] += ra.x * rb.x; acc[0][1] += ra.x * rb.y; acc[0][2] += ra.x * rb.z; acc[0][3] += ra.x * rb.w;
      acc[1][0] += ra.y * rb.x; acc[1][1] += ra.y * rb.y; acc[1][2] += ra.y * rb.z; acc[1][3] += ra.y * rb.w;
      acc[2][0] += ra.z * rb.x; acc[2][1] += ra.z * rb.y; acc[2][2] += ra.z * rb.z; acc[2][3] += ra.z * rb.w;
      acc[3][0] += ra.w * rb.x; acc[3][1] += ra.w * rb.y; acc[3][2] += ra.w * rb.z; acc[3][3] += ra.w * rb.w;
    }
  }
  int c = bn + tx * 4;
  float4 bb = *(const float4*)(bias + c);
#pragma unroll
  for (int i = 0; i < 4; i++){
    int r = bm + ty * 4 + i;
    if (r < M){
      float4 o;
      o.x = acc[i][0] + bb.x; o.y = acc[i][1] + bb.y;
      o.z = acc[i][2] + bb.z; o.w = acc[i][3] + bb.w;
      *(float4*)(out + (size_t)r * NN + c) = o;
    }
  }
}

// ---------------- edge helpers ----------------
__device__ __forceinline__ int e_src(const int* ep, int E0, int k){
  return (k < E0) ? ep[k] : (k - E0);
}
__device__ __forceinline__ int e_dst(const int* ep, int E0, int k){
  return (k < E0) ? ep[E0 + k] : (k - E0);
}

// wave per edge: e = leaky_relu(xl[src]+xr[dst]) . att ; atomic segment max
__global__ __launch_bounds__(256) void edge_score_kernel(
    const float* __restrict__ xl, const float* __restrict__ xr,
    const float* __restrict__ att, const int* __restrict__ ep,
    int E0, int E, int limit, float* __restrict__ e_out,
    unsigned* __restrict__ m_enc){
  int k = blockIdx.x * 4 + (threadIdx.x >> 6);
  if (k >= E) return;
  int d = e_dst(ep, E0, k);
  if (d >= limit) return;
  int s = e_src(ep, E0, k);
  int lane = threadIdx.x & 63;
  const float* pl = xl + (size_t)s * H;
  const float* pr = xr + (size_t)d * H;
  float sum = 0.f;
#pragma unroll
  for (int i = 0; i < 12; i++){
    int h = lane + i * 64;
    float v = pl[h] + pr[h];
    v = (v > 0.f) ? v : 0.2f * v;
    sum += v * att[h];
  }
  for (int o = 32; o; o >>= 1) sum += __shfl_down(sum, o);
  if (lane == 0){
    e_out[k] = sum;
    atomicMax(&m_enc[d], enc_f(sum));
  }
}

__global__ __launch_bounds__(256) void edge_exp_kernel(
    const float* __restrict__ e, const int* __restrict__ ep, int E0, int E,
    int limit, const unsigned* __restrict__ m_enc,
    float* __restrict__ a, float* __restrict__ denom){
  int k = blockIdx.x * 256 + threadIdx.x;
  if (k >= E) return;
  int d = e_dst(ep, E0, k);
  if (d >= limit) return;
  float av = expf(e[k] - dec_f(m_enc[d]));
  a[k] = av;
  atomicAdd(&denom[d], av);
}

// ---------------- CSR build (by dst) ----------------
__global__ __launch_bounds__(256) void count_kernel(const int* __restrict__ ep,
                                                    int E0, int E, int* __restrict__ cnt){
  int k = blockIdx.x * 256 + threadIdx.x;
  if (k >= E) return;
  atomicAdd(&cnt[e_dst(ep, E0, k)], 1);
}

__global__ __launch_bounds__(1024) void exscan_kernel(const int* __restrict__ cnt,
                                                      int* __restrict__ off, int n){
  __shared__ int lds[1024];
  __shared__ int carry;
  int tid = threadIdx.x;
  if (tid == 0) carry = 0;
  __syncthreads();
  for (int base = 0; base < n; base += 1024){
    int v = (base + tid < n) ? cnt[base + tid] : 0;
    lds[tid] = v;
    __syncthreads();
    for (int o = 1; o < 1024; o <<= 1){
      int t = (tid >= o) ? lds[tid - o] : 0;
      __syncthreads();
      lds[tid] += t;
      __syncthreads();
    }
    int inc = lds[tid];
    int c = carry;
    if (base + tid < n) off[base + tid] = c + inc - v;
    __syncthreads();
    if (tid == 1023) carry = c + lds[1023];
    __syncthreads();
  }
  if (tid == 0) off[n] = carry;
}

__global__ __launch_bounds__(256) void copy_int_kernel(const int* __restrict__ s,
                                                       int* __restrict__ d, int n){
  int i = blockIdx.x * 256 + threadIdx.x;
  if (i < n) d[i] = s[i];
}

__global__ __launch_bounds__(256) void fill_kernel(const int* __restrict__ ep, int E0, int E,
                                                   int* __restrict__ cur, int* __restrict__ csr){
  int k = blockIdx.x * 256 + threadIdx.x;
  if (k >= E) return;
  int d = e_dst(ep, E0, k);
  int pos = atomicAdd(&cur[d], 1);
  csr[pos] = k;
}

// ---------------- aggregation: block per dst node ----------------
__global__ __launch_bounds__(256) void agg_kernel(
    const float* __restrict__ xl, const float* __restrict__ a,
    const float* __restrict__ denom, const int* __restrict__ off,
    const int* __restrict__ csr, const int* __restrict__ ep, int E0,
    const float* __restrict__ bias, float* __restrict__ out){
  int d = blockIdx.x;
  int tid = threadIdx.x;
  int j0 = off[d], j1 = off[d + 1];
  float acc0 = 0.f, acc1 = 0.f, acc2 = 0.f;
  for (int j = j0; j < j1; j++){
    int k = csr[j];
    int s = e_src(ep, E0, k);
    float w = a[k];
    const float* p = xl + (size_t)s * H;
    acc0 += w * p[tid];
    acc1 += w * p[tid + 256];
    acc2 += w * p[tid + 512];
  }
  float inv = 1.0f / denom[d];
  float* op = out + (size_t)d * H;
  op[tid]       = acc0 * inv + bias[tid];
  op[tid + 256] = acc1 * inv + bias[tid + 256];
  op[tid + 512] = acc2 * inv + bias[tid + 512];
}

extern "C" void kernel_launch(void* const* d_in, const int* in_sizes, int n_in,
                              void* d_out, int out_size, void* d_ws, size_t ws_size,
                              hipStream_t stream){
  const float* emb   = (const float*)d_in[0];
  const float* feats = (const float*)d_in[1];
  const int*   edges = (const int*)d_in[2];
  const float* Wl2 = (const float*)d_in[4],  *bl2 = (const float*)d_in[5];
  const float* Wr2 = (const float*)d_in[6],  *br2 = (const float*)d_in[7];
  const float* att2= (const float*)d_in[8],  *bias2=(const float*)d_in[9];
  const float* Wl3 = (const float*)d_in[10], *bl3 = (const float*)d_in[11];
  const float* Wr3 = (const float*)d_in[12], *br3 = (const float*)d_in[13];
  const float* att3= (const float*)d_in[14], *bias3=(const float*)d_in[15];
  const float* g1 = (const float*)d_in[16], *b1 = (const float*)d_in[17];
  const float* g2 = (const float*)d_in[18], *b2 = (const float*)d_in[19];
  const float* g3 = (const float*)d_in[20], *b3 = (const float*)d_in[21];

  const int N  = in_sizes[1] / H;   // 50000
  const int E0 = in_sizes[2] / 2;   // 100000
  const int E  = E0 + N;            // 150000 (edges + self loops)
  const int L  = 4096;              // labels_size (fixed by problem spec)
  const size_t SZ = (size_t)N * H;

  float* f0 = (float*)d_ws;
  float* f1 = f0 + SZ;
  float* f2 = f1 + SZ;
  float* ebuf  = f2 + SZ;
  float* abuf  = ebuf + E;
  float* denom = abuf + E;
  unsigned* m_enc = (unsigned*)(denom + N);
  int* cnt = (int*)(m_enc + N);
  int* off = cnt + N;
  int* cur = off + N + 1;
  int* csr = cur + N;

  float* out_f = (float*)d_out;

  // output 0: passthrough copy of input_embeddings
  hipMemcpyAsync(out_f, emb, (size_t)in_sizes[0] * sizeof(float),
                 hipMemcpyDeviceToDevice, stream);

  // CSR by dst (shared by both layers)
  hipMemsetAsync(cnt, 0, (size_t)N * sizeof(int), stream);
  count_kernel<<<(E + 255) / 256, 256, 0, stream>>>(edges, E0, E, cnt);
  exscan_kernel<<<1, 1024, 0, stream>>>(cnt, off, N);
  copy_int_kernel<<<(N + 255) / 256, 256, 0, stream>>>(off, cur, N);
  fill_kernel<<<(E + 255) / 256, 256, 0, stream>>>(edges, E0, E, cur, csr);

  dim3 ggridN(12, (N + 63) / 64);
  dim3 ggridL(12, (L + 63) / 64);

  // ---- layer 1 (full N) ----
  ln_gelu_kernel<<<N, 256, 0, stream>>>(feats, g1, b1, f0, N);
  gemm_bias_kernel<<<ggridN, 256, 0, stream>>>(f0, Wl2, bl2, f1, N);   // xl
  gemm_bias_kernel<<<ggridN, 256, 0, stream>>>(f0, Wr2, br2, f2, N);   // xr
  hipMemsetAsync(m_enc, 0, (size_t)N * sizeof(unsigned), stream);
  hipMemsetAsync(denom, 0, (size_t)N * sizeof(float), stream);
  edge_score_kernel<<<(E + 3) / 4, 256, 0, stream>>>(f1, f2, att2, edges, E0, E, N, ebuf, m_enc);
  edge_exp_kernel<<<(E + 255) / 256, 256, 0, stream>>>(ebuf, edges, E0, E, N, m_enc, abuf, denom);
  agg_kernel<<<N, 256, 0, stream>>>(f1, abuf, denom, off, csr, edges, E0, bias2, f0);

  // ---- layer 2 (output only needed for rows < L) ----
  ln_gelu_kernel<<<N, 256, 0, stream>>>(f0, g2, b2, f2, N);
  gemm_bias_kernel<<<ggridN, 256, 0, stream>>>(f2, Wl3, bl3, f1, N);   // xl (all rows: arbitrary src)
  gemm_bias_kernel<<<ggridL, 256, 0, stream>>>(f2, Wr3, br3, f0, L);   // xr (only dst < L)
  hipMemsetAsync(m_enc, 0, (size_t)N * sizeof(unsigned), stream);
  hipMemsetAsync(denom, 0, (size_t)N * sizeof(float), stream);
  edge_score_kernel<<<(E + 3) / 4, 256, 0, stream>>>(f1, f0, att3, edges, E0, E, L, ebuf, m_enc);
  edge_exp_kernel<<<(E + 255) / 256, 256, 0, stream>>>(ebuf, edges, E0, E, L, m_enc, abuf, denom);
  agg_kernel<<<L, 256, 0, stream>>>(f1, abuf, denom, off, csr, edges, E0, bias3, f2);

  // final LN+GELU on the 4096 output rows, straight into d_out
  ln_gelu_kernel<<<L, 256, 0, stream>>>(f2, g3, b3, out_f + in_sizes[0], L);
}

// Round 2
// 908.377 us; speedup vs baseline: 3.2284x; 3.2284x over previous
//
#include <hip/hip_runtime.h>
#include <hip/hip_bf16.h>
#include <math.h>

#define H 768

typedef __attribute__((ext_vector_type(4))) float f32x4;
typedef __attribute__((ext_vector_type(8))) short bf16x8;

__device__ __forceinline__ float bf2f(unsigned u16v){
  return __uint_as_float((u16v & 0xffffu) << 16);
}
__device__ __forceinline__ float gelu_exact(float x){
  return 0.5f * x * (1.0f + erff(x * 0.70710678118654752f));
}
__device__ __forceinline__ unsigned enc_f(float f){
  unsigned u = __float_as_uint(f);
  return (u & 0x80000000u) ? ~u : (u | 0x80000000u);
}
__device__ __forceinline__ float dec_f(unsigned v){
  unsigned u = (v & 0x80000000u) ? (v ^ 0x80000000u) : ~v;
  return __uint_as_float(u);
}
__device__ __forceinline__ void gload16(const void* g, void* l){
  __builtin_amdgcn_global_load_lds(
      (const __attribute__((address_space(1))) unsigned int*)g,
      (__attribute__((address_space(3))) unsigned int*)l,
      16, 0, 0);
}

// ---------------- LayerNorm + exact GELU: one block (256 thr) per row ----------------
template<typename OutT>
__global__ __launch_bounds__(256) void ln_gelu_kernel(
    const float* __restrict__ in, const float* __restrict__ g,
    const float* __restrict__ b, OutT* __restrict__ out, int rows){
  int row = blockIdx.x;
  if (row >= rows) return;
  int tid = threadIdx.x;
  const float* rp = in + (size_t)row * H;
  float v0 = rp[tid], v1 = rp[tid + 256], v2 = rp[tid + 512];
  __shared__ float red[4];
  int lane = tid & 63, wid = tid >> 6;
  float s = v0 + v1 + v2;
  for (int o = 32; o; o >>= 1) s += __shfl_down(s, o);
  if (lane == 0) red[wid] = s;
  __syncthreads();
  float mean = (red[0] + red[1] + red[2] + red[3]) * (1.0f / H);
  __syncthreads();
  float d0 = v0 - mean, d1 = v1 - mean, d2 = v2 - mean;
  s = d0*d0 + d1*d1 + d2*d2;
  for (int o = 32; o; o >>= 1) s += __shfl_down(s, o);
  if (lane == 0) red[wid] = s;
  __syncthreads();
  float var = (red[0] + red[1] + red[2] + red[3]) * (1.0f / H);
  float rstd = rsqrtf(var + 1e-5f);
  OutT* op = out + (size_t)row * H;
  float y0 = gelu_exact(d0 * rstd * g[tid]       + b[tid]);
  float y1 = gelu_exact(d1 * rstd * g[tid + 256] + b[tid + 256]);
  float y2 = gelu_exact(d2 * rstd * g[tid + 512] + b[tid + 512]);
  if constexpr (sizeof(OutT) == 2){
    op[tid]       = __float2bfloat16(y0);
    op[tid + 256] = __float2bfloat16(y1);
    op[tid + 512] = __float2bfloat16(y2);
  } else {
    op[tid]       = y0;
    op[tid + 256] = y1;
    op[tid + 512] = y2;
  }
}

// ---------------- weight transpose + f32->bf16: WT[n][k] = W[k][n] ----------------
__global__ __launch_bounds__(256) void wt_bf16_kernel(
    const float* __restrict__ W, __hip_bfloat16* __restrict__ WT){
  __shared__ float tile[32][33];
  int k0 = blockIdx.x * 32, n0 = blockIdx.y * 32;
  int tx = threadIdx.x & 31, ty = threadIdx.x >> 5;   // 32 x 8
#pragma unroll
  for (int i = 0; i < 32; i += 8)
    tile[ty + i][tx] = W[(size_t)(k0 + ty + i) * H + n0 + tx];
  __syncthreads();
#pragma unroll
  for (int i = 0; i < 32; i += 8)
    WT[(size_t)(n0 + ty + i) * H + k0 + tx] = __float2bfloat16(tile[tx][ty + i]);
}

// ---------------- bf16 MFMA GEMM: C[M,768] = A[Mpad,768] @ BT^T + bias ----------------
// BT is row-major [768][768] holding W^T. 128x128 tile, BK=32, 4 waves (2x2).
__global__ __launch_bounds__(256) void gemm_mfma_kernel(
    const __hip_bfloat16* __restrict__ A,
    const __hip_bfloat16* __restrict__ BT,
    const float* __restrict__ bias,
    __hip_bfloat16* __restrict__ C, int M){
  __shared__ __hip_bfloat16 As[128][32];
  __shared__ __hip_bfloat16 Bs[128][32];
  const int t = threadIdx.x;
  const int bn = blockIdx.x * 128;
  const int bm = blockIdx.y * 128;
  const int srow = t >> 2, scol = (t & 3) * 8;     // staging map: t*16B linear in LDS
  const __hip_bfloat16* ga0 = A  + (size_t)(bm + srow) * H + scol;
  const __hip_bfloat16* ga1 = ga0 + (size_t)64 * H;
  const __hip_bfloat16* gb0 = BT + (size_t)(bn + srow) * H + scol;
  const __hip_bfloat16* gb1 = gb0 + (size_t)64 * H;
  __hip_bfloat16* la0 = &As[srow][scol];
  __hip_bfloat16* la1 = &As[srow + 64][scol];
  __hip_bfloat16* lb0 = &Bs[srow][scol];
  __hip_bfloat16* lb1 = &Bs[srow + 64][scol];

  const int l = t & 63, w = t >> 6;
  const int wm = (w >> 1) * 64, wn = (w & 1) * 64;
  const int r0 = l & 15, kc = (l >> 4) * 8;

  f32x4 acc[4][4];
#pragma unroll
  for (int m = 0; m < 4; m++)
#pragma unroll
    for (int n = 0; n < 4; n++) acc[m][n] = (f32x4){0.f, 0.f, 0.f, 0.f};

  for (int k0 = 0; k0 < H; k0 += 32){
    __syncthreads();                       // prev iter's frag reads done
    gload16(ga0 + k0, la0);
    gload16(ga1 + k0, la1);
    gload16(gb0 + k0, lb0);
    gload16(gb1 + k0, lb1);
    __syncthreads();                       // drains vmcnt before barrier
    bf16x8 af[4], bfr[4];
#pragma unroll
    for (int m = 0; m < 4; m++) af[m]  = *(const bf16x8*)&As[wm + m * 16 + r0][kc];
#pragma unroll
    for (int n = 0; n < 4; n++) bfr[n] = *(const bf16x8*)&Bs[wn + n * 16 + r0][kc];
#pragma unroll
    for (int m = 0; m < 4; m++)
#pragma unroll
      for (int n = 0; n < 4; n++)
        acc[m][n] = __builtin_amdgcn_mfma_f32_16x16x32_bf16(af[m], bfr[n], acc[m][n], 0, 0, 0);
  }

  const int rgrp = (l >> 4) * 4;
#pragma unroll
  for (int n = 0; n < 4; n++){
    int c = bn + wn + n * 16 + r0;
    float bb = bias[c];
#pragma unroll
    for (int m = 0; m < 4; m++){
      int rb = bm + wm + m * 16 + rgrp;
#pragma unroll
      for (int j = 0; j < 4; j++){
        int r = rb + j;
        if (r < M) C[(size_t)r * H + c] = __float2bfloat16(acc[m][n][j] + bb);
      }
    }
  }
}

// ---------------- edge helpers ----------------
__device__ __forceinline__ int e_src(const int* ep, int E0, int k){
  return (k < E0) ? ep[k] : (k - E0);
}
__device__ __forceinline__ int e_dst(const int* ep, int E0, int k){
  return (k < E0) ? ep[E0 + k] : (k - E0);
}

// wave per edge: e = leaky_relu(xl[src]+xr[dst]) . att ; atomic segment max
__global__ __launch_bounds__(256) void edge_score_kernel(
    const __hip_bfloat16* __restrict__ xl, const __hip_bfloat16* __restrict__ xr,
    const float* __restrict__ att, const int* __restrict__ ep,
    int E0, int E, int limit, float* __restrict__ e_out,
    unsigned* __restrict__ m_enc){
  int k = blockIdx.x * 4 + (threadIdx.x >> 6);
  if (k >= E) return;
  int d = e_dst(ep, E0, k);
  if (d >= limit) return;
  int s = e_src(ep, E0, k);
  int lane = threadIdx.x & 63;
  const unsigned* pl = (const unsigned*)(xl + (size_t)s * H);
  const unsigned* pr = (const unsigned*)(xr + (size_t)d * H);
  float sum = 0.f;
#pragma unroll
  for (int i = 0; i < 3; i++){
    int h2 = lane * 2 + i * 128;          // index in units of 2 bf16 (4B)
    uint2 vl = *(const uint2*)&pl[h2];
    uint2 vr = *(const uint2*)&pr[h2];
    float4 av = *(const float4*)&att[h2 * 2];
    float v;
    v = bf2f(vl.x) + bf2f(vr.x);             v = v > 0.f ? v : 0.2f * v; sum += v * av.x;
    v = bf2f(vl.x >> 16) + bf2f(vr.x >> 16); v = v > 0.f ? v : 0.2f * v; sum += v * av.y;
    v = bf2f(vl.y) + bf2f(vr.y);             v = v > 0.f ? v : 0.2f * v; sum += v * av.z;
    v = bf2f(vl.y >> 16) + bf2f(vr.y >> 16); v = v > 0.f ? v : 0.2f * v; sum += v * av.w;
  }
  for (int o = 32; o; o >>= 1) sum += __shfl_down(sum, o);
  if (lane == 0){
    e_out[k] = sum;
    atomicMax(&m_enc[d], enc_f(sum));
  }
}

__global__ __launch_bounds__(256) void edge_exp_kernel(
    const float* __restrict__ e, const int* __restrict__ ep, int E0, int E,
    int limit, const unsigned* __restrict__ m_enc,
    float* __restrict__ a, float* __restrict__ denom){
  int k = blockIdx.x * 256 + threadIdx.x;
  if (k >= E) return;
  int d = e_dst(ep, E0, k);
  if (d >= limit) return;
  float av = expf(e[k] - dec_f(m_enc[d]));
  a[k] = av;
  atomicAdd(&denom[d], av);
}

// ---------------- CSR build (by dst) ----------------
__global__ __launch_bounds__(256) void count_kernel(const int* __restrict__ ep,
                                                    int E0, int E, int* __restrict__ cnt){
  int k = blockIdx.x * 256 + threadIdx.x;
  if (k >= E) return;
  atomicAdd(&cnt[e_dst(ep, E0, k)], 1);
}

__global__ __launch_bounds__(1024) void exscan_kernel(const int* __restrict__ cnt,
                                                      int* __restrict__ off, int n){
  __shared__ int lds[1024];
  __shared__ int carry;
  int tid = threadIdx.x;
  if (tid == 0) carry = 0;
  __syncthreads();
  for (int base = 0; base < n; base += 1024){
    int v = (base + tid < n) ? cnt[base + tid] : 0;
    lds[tid] = v;
    __syncthreads();
    for (int o = 1; o < 1024; o <<= 1){
      int tv = (tid >= o) ? lds[tid - o] : 0;
      __syncthreads();
      lds[tid] += tv;
      __syncthreads();
    }
    int inc = lds[tid];
    int c = carry;
    if (base + tid < n) off[base + tid] = c + inc - v;
    __syncthreads();
    if (tid == 1023) carry = c + lds[1023];
    __syncthreads();
  }
  if (tid == 0) off[n] = carry;
}

__global__ __launch_bounds__(256) void copy_int_kernel(const int* __restrict__ s,
                                                       int* __restrict__ d, int n){
  int i = blockIdx.x * 256 + threadIdx.x;
  if (i < n) d[i] = s[i];
}

__global__ __launch_bounds__(256) void fill_kernel(const int* __restrict__ ep, int E0, int E,
                                                   int* __restrict__ cur, int* __restrict__ csr){
  int k = blockIdx.x * 256 + threadIdx.x;
  if (k >= E) return;
  int d = e_dst(ep, E0, k);
  int pos = atomicAdd(&cur[d], 1);
  csr[pos] = k;
}

// ---------------- aggregation: block per dst node ----------------
__global__ __launch_bounds__(256) void agg_kernel(
    const __hip_bfloat16* __restrict__ xl, const float* __restrict__ a,
    const float* __restrict__ denom, const int* __restrict__ off,
    const int* __restrict__ csr, const int* __restrict__ ep, int E0,
    const float* __restrict__ bias, float* __restrict__ out){
  int d = blockIdx.x;
  int tid = threadIdx.x;
  int j0 = off[d], j1 = off[d + 1];
  float acc0 = 0.f, acc1 = 0.f, acc2 = 0.f;
  for (int j = j0; j < j1; j++){
    int k = csr[j];
    int s = e_src(ep, E0, k);
    float wgt = a[k];
    const unsigned short* p = (const unsigned short*)(xl + (size_t)s * H);
    acc0 += wgt * bf2f(p[tid]);
    acc1 += wgt * bf2f(p[tid + 256]);
    acc2 += wgt * bf2f(p[tid + 512]);
  }
  float inv = 1.0f / denom[d];
  float* op = out + (size_t)d * H;
  op[tid]       = acc0 * inv + bias[tid];
  op[tid + 256] = acc1 * inv + bias[tid + 256];
  op[tid + 512] = acc2 * inv + bias[tid + 512];
}

extern "C" void kernel_launch(void* const* d_in, const int* in_sizes, int n_in,
                              void* d_out, int out_size, void* d_ws, size_t ws_size,
                              hipStream_t stream){
  const float* emb   = (const float*)d_in[0];
  const float* feats = (const float*)d_in[1];
  const int*   edges = (const int*)d_in[2];
  const float* Wl2 = (const float*)d_in[4],  *bl2 = (const float*)d_in[5];
  const float* Wr2 = (const float*)d_in[6],  *br2 = (const float*)d_in[7];
  const float* att2= (const float*)d_in[8],  *bias2=(const float*)d_in[9];
  const float* Wl3 = (const float*)d_in[10], *bl3 = (const float*)d_in[11];
  const float* Wr3 = (const float*)d_in[12], *br3 = (const float*)d_in[13];
  const float* att3= (const float*)d_in[14], *bias3=(const float*)d_in[15];
  const float* g1 = (const float*)d_in[16], *b1 = (const float*)d_in[17];
  const float* g2 = (const float*)d_in[18], *b2 = (const float*)d_in[19];
  const float* g3 = (const float*)d_in[20], *b3 = (const float*)d_in[21];

  const int N  = in_sizes[1] / H;             // 50000
  const int E0 = in_sizes[2] / 2;             // 100000
  const int E  = E0 + N;                      // 150000
  const int L  = 4096;                        // labels_size
  const int Mpad = ((N + 127) / 128) * 128;   // 50048

  __hip_bfloat16* ab   = (__hip_bfloat16*)d_ws;          // [Mpad][H] GEMM input
  __hip_bfloat16* xl   = ab + (size_t)Mpad * H;          // [N][H]
  __hip_bfloat16* xr   = xl + (size_t)N * H;             // [N][H]
  __hip_bfloat16* wtl2 = xr + (size_t)N * H;
  __hip_bfloat16* wtr2 = wtl2 + (size_t)H * H;
  __hip_bfloat16* wtl3 = wtr2 + (size_t)H * H;
  __hip_bfloat16* wtr3 = wtl3 + (size_t)H * H;
  float* gout  = (float*)(wtr3 + (size_t)H * H);         // [N][H] agg output
  float* ebuf  = gout + (size_t)N * H;
  float* abuf  = ebuf + E;
  float* denom = abuf + E;
  unsigned* m_enc = (unsigned*)(denom + N);
  int* cnt = (int*)(m_enc + N);
  int* off = cnt + N;
  int* cur = off + N + 1;
  int* csr = cur + N;

  float* out_f = (float*)d_out;

  // output 0: passthrough copy of input_embeddings
  hipMemcpyAsync(out_f, emb, (size_t)in_sizes[0] * sizeof(float),
                 hipMemcpyDeviceToDevice, stream);

  // CSR by dst (shared by both layers)
  hipMemsetAsync(cnt, 0, (size_t)N * sizeof(int), stream);
  count_kernel<<<(E + 255) / 256, 256, 0, stream>>>(edges, E0, E, cnt);
  exscan_kernel<<<1, 1024, 0, stream>>>(cnt, off, N);
  copy_int_kernel<<<(N + 255) / 256, 256, 0, stream>>>(off, cur, N);
  fill_kernel<<<(E + 255) / 256, 256, 0, stream>>>(edges, E0, E, cur, csr);

  // weights -> bf16 transposed
  dim3 wgrid(H / 32, H / 32);
  wt_bf16_kernel<<<wgrid, 256, 0, stream>>>(Wl2, wtl2);
  wt_bf16_kernel<<<wgrid, 256, 0, stream>>>(Wr2, wtr2);
  wt_bf16_kernel<<<wgrid, 256, 0, stream>>>(Wl3, wtl3);
  wt_bf16_kernel<<<wgrid, 256, 0, stream>>>(Wr3, wtr3);

  dim3 ggN(H / 128, Mpad / 128);
  dim3 ggL(H / 128, L / 128);

  // ---- layer 1 (full N) ----
  ln_gelu_kernel<__hip_bfloat16><<<N, 256, 0, stream>>>(feats, g1, b1, ab, N);
  gemm_mfma_kernel<<<ggN, 256, 0, stream>>>(ab, wtl2, bl2, xl, N);
  gemm_mfma_kernel<<<ggN, 256, 0, stream>>>(ab, wtr2, br2, xr, N);
  hipMemsetAsync(m_enc, 0, (size_t)N * sizeof(unsigned), stream);
  hipMemsetAsync(denom, 0, (size_t)N * sizeof(float), stream);
  edge_score_kernel<<<(E + 3) / 4, 256, 0, stream>>>(xl, xr, att2, edges, E0, E, N, ebuf, m_enc);
  edge_exp_kernel<<<(E + 255) / 256, 256, 0, stream>>>(ebuf, edges, E0, E, N, m_enc, abuf, denom);
  agg_kernel<<<N, 256, 0, stream>>>(xl, abuf, denom, off, csr, edges, E0, bias2, gout);

  // ---- layer 2 (output only needed for rows < L) ----
  ln_gelu_kernel<__hip_bfloat16><<<N, 256, 0, stream>>>(gout, g2, b2, ab, N);
  gemm_mfma_kernel<<<ggN, 256, 0, stream>>>(ab, wtl3, bl3, xl, N);   // xl: all rows (src arbitrary)
  gemm_mfma_kernel<<<ggL, 256, 0, stream>>>(ab, wtr3, br3, xr, L);   // xr: only dst < L
  hipMemsetAsync(m_enc, 0, (size_t)N * sizeof(unsigned), stream);
  hipMemsetAsync(denom, 0, (size_t)N * sizeof(float), stream);
  edge_score_kernel<<<(E + 3) / 4, 256, 0, stream>>>(xl, xr, att3, edges, E0, E, L, ebuf, m_enc);
  edge_exp_kernel<<<(E + 255) / 256, 256, 0, stream>>>(ebuf, edges, E0, E, L, m_enc, abuf, denom);
  agg_kernel<<<L, 256, 0, stream>>>(xl, abuf, denom, off, csr, edges, E0, bias3, gout);

  // final LN+GELU on the 4096 output rows, straight into d_out
  ln_gelu_kernel<float><<<L, 256, 0, stream>>>(gout, g3, b3, out_f + in_sizes[0], L);
}

// Round 3
// 798.563 us; speedup vs baseline: 3.6724x; 1.1375x over previous
//
#include <hip/hip_runtime.h>
#include <hip/hip_bf16.h>
#include <math.h>

#define H 768
#define BM 128

typedef __attribute__((ext_vector_type(4))) float f32x4;
typedef __attribute__((ext_vector_type(8))) short bf16x8;

__device__ __forceinline__ float bf2f(unsigned u16v){
  return __uint_as_float((u16v & 0xffffu) << 16);
}
__device__ __forceinline__ float gelu_exact(float x){
  return 0.5f * x * (1.0f + erff(x * 0.70710678118654752f));
}
__device__ __forceinline__ unsigned enc_f(float f){
  unsigned u = __float_as_uint(f);
  return (u & 0x80000000u) ? ~u : (u | 0x80000000u);
}
__device__ __forceinline__ float dec_f(unsigned v){
  unsigned u = (v & 0x80000000u) ? (v ^ 0x80000000u) : ~v;
  return __uint_as_float(u);
}
__device__ __forceinline__ void gload16(const void* g, void* l){
  __builtin_amdgcn_global_load_lds(
      (const __attribute__((address_space(1))) unsigned int*)g,
      (__attribute__((address_space(3))) unsigned int*)l,
      16, 0, 0);
}

// ---------------- LayerNorm + exact GELU: one block (256 thr) per row ----------------
template<typename OutT>
__global__ __launch_bounds__(256) void ln_gelu_kernel(
    const float* __restrict__ in, const float* __restrict__ g,
    const float* __restrict__ b, OutT* __restrict__ out, int rows){
  int row = blockIdx.x;
  if (row >= rows) return;
  int tid = threadIdx.x;
  const float* rp = in + (size_t)row * H;
  float v0 = rp[tid], v1 = rp[tid + 256], v2 = rp[tid + 512];
  __shared__ float red[4];
  int lane = tid & 63, wid = tid >> 6;
  float s = v0 + v1 + v2;
  for (int o = 32; o; o >>= 1) s += __shfl_down(s, o);
  if (lane == 0) red[wid] = s;
  __syncthreads();
  float mean = (red[0] + red[1] + red[2] + red[3]) * (1.0f / H);
  __syncthreads();
  float d0 = v0 - mean, d1 = v1 - mean, d2 = v2 - mean;
  s = d0*d0 + d1*d1 + d2*d2;
  for (int o = 32; o; o >>= 1) s += __shfl_down(s, o);
  if (lane == 0) red[wid] = s;
  __syncthreads();
  float var = (red[0] + red[1] + red[2] + red[3]) * (1.0f / H);
  float rstd = rsqrtf(var + 1e-5f);
  OutT* op = out + (size_t)row * H;
  float y0 = gelu_exact(d0 * rstd * g[tid]       + b[tid]);
  float y1 = gelu_exact(d1 * rstd * g[tid + 256] + b[tid + 256]);
  float y2 = gelu_exact(d2 * rstd * g[tid + 512] + b[tid + 512]);
  if constexpr (sizeof(OutT) == 2){
    op[tid]       = __float2bfloat16(y0);
    op[tid + 256] = __float2bfloat16(y1);
    op[tid + 512] = __float2bfloat16(y2);
  } else {
    op[tid]       = y0;
    op[tid + 256] = y1;
    op[tid + 512] = y2;
  }
}

// ---------------- weight transpose + f32->bf16: WT[n][k] = W[k][n] ----------------
__global__ __launch_bounds__(256) void wt_bf16_kernel(
    const float* __restrict__ W, __hip_bfloat16* __restrict__ WT){
  __shared__ float tile[32][33];
  int k0 = blockIdx.x * 32, n0 = blockIdx.y * 32;
  int tx = threadIdx.x & 31, ty = threadIdx.x >> 5;   // 32 x 8
#pragma unroll
  for (int i = 0; i < 32; i += 8)
    tile[ty + i][tx] = W[(size_t)(k0 + ty + i) * H + n0 + tx];
  __syncthreads();
#pragma unroll
  for (int i = 0; i < 32; i += 8)
    WT[(size_t)(n0 + ty + i) * H + k0 + tx] = __float2bfloat16(tile[tx][ty + i]);
}

// ---------------- fused bf16 MFMA GEMM ----------------
// Computes [Cl | Cr] = A[panels*128,768] @ WT[1536,768]^T (+bias), where
// WT rows 0..767 = Wl^T (-> Cl), rows 768..1535 = Wr^T (-> Cr, rows < Mr only).
// 128x128 tile, BK=32 double-buffered, 4 waves, XCD-aware panel swizzle,
// XOR-swizzled LDS (pre-swizzled global source, rule #21), LDS-staged C write.
__global__ __launch_bounds__(256) void gemm_fused_kernel(
    const __hip_bfloat16* __restrict__ A,
    const __hip_bfloat16* __restrict__ WT,
    const float* __restrict__ bl, const float* __restrict__ br,
    __hip_bfloat16* __restrict__ Cl, __hip_bfloat16* __restrict__ Cr,
    int panels, int Mr){
  __shared__ char smem[32768];
  typedef __hip_bfloat16 tile_t[128][32];
  tile_t* As = (tile_t*)smem;                 // As[2]: 16KB
  tile_t* Bs = (tile_t*)(smem + 16384);       // Bs[2]: 16KB

  // bijective XCD swizzle: all 12 column-blocks of a panel land consecutively
  // on the same XCD (panels % 8 == 0 guaranteed by padding).
  int wgid = blockIdx.x;
  int xcd = wgid & 7, j = wgid >> 3;
  int panel = xcd * (panels >> 3) + j / 12;
  int colblk = j % 12;
  int row0 = panel * BM;
  const bool is_r = colblk >= 6;
  if (is_r && row0 >= Mr) return;

  const int t = threadIdx.x;
  const int sr = t >> 2, sc = (t & 3) * 8;            // linear LDS slot
  const int scs = sc ^ ((sr & 3) << 3);               // pre-swizzled global col
  const __hip_bfloat16* pa0 = A + (size_t)(row0 + sr) * H + scs;
  const __hip_bfloat16* pa1 = pa0 + (size_t)64 * H;
  const __hip_bfloat16* pb0 = WT + (size_t)(colblk * 128 + sr) * H + scs;
  const __hip_bfloat16* pb1 = pb0 + (size_t)64 * H;

  const int l = t & 63, w = t >> 6;
  const int wm = (w >> 1) * 64, wn = (w & 1) * 64;
  const int r0 = l & 15;
  const int kcs = ((l >> 4) * 8) ^ ((r0 & 3) << 3);   // swizzled frag col

  f32x4 acc[4][4];
#pragma unroll
  for (int m = 0; m < 4; m++)
#pragma unroll
    for (int n = 0; n < 4; n++) acc[m][n] = (f32x4){0.f, 0.f, 0.f, 0.f};

  // prologue: stage K-tile 0 into buffer 0
  gload16(pa0, &As[0][sr][sc]);
  gload16(pa1, &As[0][sr + 64][sc]);
  gload16(pb0, &Bs[0][sr][sc]);
  gload16(pb1, &Bs[0][sr + 64][sc]);
  __syncthreads();

  int cur = 0;
  for (int kt = 0; kt < H / 32; kt++){
    if (kt + 1 < H / 32){                  // issue next-tile loads (overlap compute)
      int k0 = (kt + 1) * 32;
      int nb = cur ^ 1;
      gload16(pa0 + k0, &As[nb][sr][sc]);
      gload16(pa1 + k0, &As[nb][sr + 64][sc]);
      gload16(pb0 + k0, &Bs[nb][sr][sc]);
      gload16(pb1 + k0, &Bs[nb][sr + 64][sc]);
    }
    bf16x8 af[4], bfr[4];
#pragma unroll
    for (int m = 0; m < 4; m++) af[m]  = *(const bf16x8*)&As[cur][wm + m * 16 + r0][kcs];
#pragma unroll
    for (int n = 0; n < 4; n++) bfr[n] = *(const bf16x8*)&Bs[cur][wn + n * 16 + r0][kcs];
#pragma unroll
    for (int m = 0; m < 4; m++)
#pragma unroll
      for (int n = 0; n < 4; n++)
        acc[m][n] = __builtin_amdgcn_mfma_f32_16x16x32_bf16(af[m], bfr[n], acc[m][n], 0, 0, 0);
    __syncthreads();                       // drains vmcnt (next tile ready) + all reads done
    cur ^= 1;
  }

  // epilogue: stage C tile in LDS (conflict-free XOR layout), then 16B stores
  const int rgrp = (l >> 4) * 4;
  const float* bp = is_r ? br : bl;
  const int cb = (is_r ? colblk - 6 : colblk) * 128;
#pragma unroll
  for (int n = 0; n < 4; n++){
    int lc = wn + n * 16 + r0;
    float bb = bp[cb + lc];
#pragma unroll
    for (int m = 0; m < 4; m++){
#pragma unroll
      for (int jj = 0; jj < 4; jj++){
        int lr = wm + m * 16 + rgrp + jj;
        int byte = lr * 256 + ((lc * 2) ^ (((lr >> 2) & 3) << 5));
        *(__hip_bfloat16*)(smem + byte) = __float2bfloat16(acc[m][n][jj] + bb);
      }
    }
  }
  __syncthreads();
  __hip_bfloat16* C = is_r ? Cr : Cl;
#pragma unroll
  for (int p = 0; p < 8; p++){
    int ba = p * 4096 + t * 16;
    int lr = ba >> 8, inner = ba & 255;
    uint4 v = *(const uint4*)(smem + lr * 256 + (inner ^ (((lr >> 2) & 3) << 5)));
    *(uint4*)(C + (size_t)(row0 + lr) * H + cb + (inner >> 1)) = v;
  }
}

// ---------------- edge helpers ----------------
__device__ __forceinline__ int e_src(const int* ep, int E0, int k){
  return (k < E0) ? ep[k] : (k - E0);
}
__device__ __forceinline__ int e_dst(const int* ep, int E0, int k){
  return (k < E0) ? ep[E0 + k] : (k - E0);
}

// wave per edge: e = leaky_relu(xl[src]+xr[dst]) . att ; atomic segment max
__global__ __launch_bounds__(256) void edge_score_kernel(
    const __hip_bfloat16* __restrict__ xl, const __hip_bfloat16* __restrict__ xr,
    const float* __restrict__ att, const int* __restrict__ ep,
    int E0, int E, int limit, float* __restrict__ e_out,
    unsigned* __restrict__ m_enc){
  int k = blockIdx.x * 4 + (threadIdx.x >> 6);
  if (k >= E) return;
  int d = e_dst(ep, E0, k);
  if (d >= limit) return;
  int s = e_src(ep, E0, k);
  int lane = threadIdx.x & 63;
  const unsigned* pl = (const unsigned*)(xl + (size_t)s * H);
  const unsigned* pr = (const unsigned*)(xr + (size_t)d * H);
  float sum = 0.f;
#pragma unroll
  for (int i = 0; i < 3; i++){
    int h2 = lane * 2 + i * 128;
    uint2 vl = *(const uint2*)&pl[h2];
    uint2 vr = *(const uint2*)&pr[h2];
    float4 av = *(const float4*)&att[h2 * 2];
    float v;
    v = bf2f(vl.x) + bf2f(vr.x);             v = v > 0.f ? v : 0.2f * v; sum += v * av.x;
    v = bf2f(vl.x >> 16) + bf2f(vr.x >> 16); v = v > 0.f ? v : 0.2f * v; sum += v * av.y;
    v = bf2f(vl.y) + bf2f(vr.y);             v = v > 0.f ? v : 0.2f * v; sum += v * av.z;
    v = bf2f(vl.y >> 16) + bf2f(vr.y >> 16); v = v > 0.f ? v : 0.2f * v; sum += v * av.w;
  }
  for (int o = 32; o; o >>= 1) sum += __shfl_down(sum, o);
  if (lane == 0){
    e_out[k] = sum;
    atomicMax(&m_enc[d], enc_f(sum));
  }
}

__global__ __launch_bounds__(256) void edge_exp_kernel(
    const float* __restrict__ e, const int* __restrict__ ep, int E0, int E,
    int limit, const unsigned* __restrict__ m_enc,
    float* __restrict__ a, float* __restrict__ denom){
  int k = blockIdx.x * 256 + threadIdx.x;
  if (k >= E) return;
  int d = e_dst(ep, E0, k);
  if (d >= limit) return;
  float av = expf(e[k] - dec_f(m_enc[d]));
  a[k] = av;
  atomicAdd(&denom[d], av);
}

// ---------------- CSR build (by dst) ----------------
__global__ __launch_bounds__(256) void count_kernel(const int* __restrict__ ep,
                                                    int E0, int E, int* __restrict__ cnt){
  int k = blockIdx.x * 256 + threadIdx.x;
  if (k >= E) return;
  atomicAdd(&cnt[e_dst(ep, E0, k)], 1);
}

__global__ __launch_bounds__(1024) void exscan_kernel(const int* __restrict__ cnt,
                                                      int* __restrict__ off, int n){
  __shared__ int lds[1024];
  __shared__ int carry;
  int tid = threadIdx.x;
  if (tid == 0) carry = 0;
  __syncthreads();
  for (int base = 0; base < n; base += 1024){
    int v = (base + tid < n) ? cnt[base + tid] : 0;
    lds[tid] = v;
    __syncthreads();
    for (int o = 1; o < 1024; o <<= 1){
      int tv = (tid >= o) ? lds[tid - o] : 0;
      __syncthreads();
      lds[tid] += tv;
      __syncthreads();
    }
    int inc = lds[tid];
    int c = carry;
    if (base + tid < n) off[base + tid] = c + inc - v;
    __syncthreads();
    if (tid == 1023) carry = c + lds[1023];
    __syncthreads();
  }
  if (tid == 0) off[n] = carry;
}

__global__ __launch_bounds__(256) void copy_int_kernel(const int* __restrict__ s,
                                                       int* __restrict__ d, int n){
  int i = blockIdx.x * 256 + threadIdx.x;
  if (i < n) d[i] = s[i];
}

__global__ __launch_bounds__(256) void fill_kernel(const int* __restrict__ ep, int E0, int E,
                                                   int* __restrict__ cur, int* __restrict__ csr){
  int k = blockIdx.x * 256 + threadIdx.x;
  if (k >= E) return;
  int d = e_dst(ep, E0, k);
  int pos = atomicAdd(&cur[d], 1);
  csr[pos] = k;
}

// ---------------- aggregation: block per dst node ----------------
__global__ __launch_bounds__(256) void agg_kernel(
    const __hip_bfloat16* __restrict__ xl, const float* __restrict__ a,
    const float* __restrict__ denom, const int* __restrict__ off,
    const int* __restrict__ csr, const int* __restrict__ ep, int E0,
    const float* __restrict__ bias, float* __restrict__ out){
  int d = blockIdx.x;
  int tid = threadIdx.x;
  int j0 = off[d], j1 = off[d + 1];
  float acc0 = 0.f, acc1 = 0.f, acc2 = 0.f;
  for (int j = j0; j < j1; j++){
    int k = csr[j];
    int s = e_src(ep, E0, k);
    float wgt = a[k];
    const unsigned short* p = (const unsigned short*)(xl + (size_t)s * H);
    acc0 += wgt * bf2f(p[tid]);
    acc1 += wgt * bf2f(p[tid + 256]);
    acc2 += wgt * bf2f(p[tid + 512]);
  }
  float inv = 1.0f / denom[d];
  float* op = out + (size_t)d * H;
  op[tid]       = acc0 * inv + bias[tid];
  op[tid + 256] = acc1 * inv + bias[tid + 256];
  op[tid + 512] = acc2 * inv + bias[tid + 512];
}

extern "C" void kernel_launch(void* const* d_in, const int* in_sizes, int n_in,
                              void* d_out, int out_size, void* d_ws, size_t ws_size,
                              hipStream_t stream){
  const float* emb   = (const float*)d_in[0];
  const float* feats = (const float*)d_in[1];
  const int*   edges = (const int*)d_in[2];
  const float* Wl2 = (const float*)d_in[4],  *bl2 = (const float*)d_in[5];
  const float* Wr2 = (const float*)d_in[6],  *br2 = (const float*)d_in[7];
  const float* att2= (const float*)d_in[8],  *bias2=(const float*)d_in[9];
  const float* Wl3 = (const float*)d_in[10], *bl3 = (const float*)d_in[11];
  const float* Wr3 = (const float*)d_in[12], *br3 = (const float*)d_in[13];
  const float* att3= (const float*)d_in[14], *bias3=(const float*)d_in[15];
  const float* g1 = (const float*)d_in[16], *b1 = (const float*)d_in[17];
  const float* g2 = (const float*)d_in[18], *b2 = (const float*)d_in[19];
  const float* g3 = (const float*)d_in[20], *b3 = (const float*)d_in[21];

  const int N  = in_sizes[1] / H;             // 50000
  const int E0 = in_sizes[2] / 2;             // 100000
  const int E  = E0 + N;                      // 150000
  const int L  = 4096;                        // labels_size
  // pad panels to a multiple of 8 so the XCD swizzle is bijective
  const int panels = ((N + BM - 1) / BM + 7) & ~7;   // 392
  const int Mpad = panels * BM;                       // 50176

  __hip_bfloat16* ab  = (__hip_bfloat16*)d_ws;          // [Mpad][H] GEMM input
  __hip_bfloat16* xl  = ab + (size_t)Mpad * H;          // [Mpad][H]
  __hip_bfloat16* xr  = xl + (size_t)Mpad * H;          // [Mpad][H]
  __hip_bfloat16* wt2 = xr + (size_t)Mpad * H;          // [1536][H]
  __hip_bfloat16* wt3 = wt2 + (size_t)2 * H * H;        // [1536][H]
  float* gout  = (float*)(wt3 + (size_t)2 * H * H);     // [N][H] agg output
  float* ebuf  = gout + (size_t)N * H;
  float* abuf  = ebuf + E;
  float* denom = abuf + E;
  unsigned* m_enc = (unsigned*)(denom + N);
  int* cnt = (int*)(m_enc + N);
  int* off = cnt + N;
  int* cur = off + N + 1;
  int* csr = cur + N;

  float* out_f = (float*)d_out;

  // output 0: passthrough copy of input_embeddings
  hipMemcpyAsync(out_f, emb, (size_t)in_sizes[0] * sizeof(float),
                 hipMemcpyDeviceToDevice, stream);

  // CSR by dst (shared by both layers)
  hipMemsetAsync(cnt, 0, (size_t)N * sizeof(int), stream);
  count_kernel<<<(E + 255) / 256, 256, 0, stream>>>(edges, E0, E, cnt);
  exscan_kernel<<<1, 1024, 0, stream>>>(cnt, off, N);
  copy_int_kernel<<<(N + 255) / 256, 256, 0, stream>>>(off, cur, N);
  fill_kernel<<<(E + 255) / 256, 256, 0, stream>>>(edges, E0, E, cur, csr);

  // weights -> bf16 transposed, concatenated [Wl^T ; Wr^T]
  dim3 wgrid(H / 32, H / 32);
  wt_bf16_kernel<<<wgrid, 256, 0, stream>>>(Wl2, wt2);
  wt_bf16_kernel<<<wgrid, 256, 0, stream>>>(Wr2, wt2 + (size_t)H * H);
  wt_bf16_kernel<<<wgrid, 256, 0, stream>>>(Wl3, wt3);
  wt_bf16_kernel<<<wgrid, 256, 0, stream>>>(Wr3, wt3 + (size_t)H * H);

  const int gblocks = panels * 12;

  // ---- layer 1 (full N) ----
  ln_gelu_kernel<__hip_bfloat16><<<N, 256, 0, stream>>>(feats, g1, b1, ab, N);
  gemm_fused_kernel<<<gblocks, 256, 0, stream>>>(ab, wt2, bl2, br2, xl, xr, panels, Mpad);
  hipMemsetAsync(m_enc, 0, (size_t)N * sizeof(unsigned), stream);
  hipMemsetAsync(denom, 0, (size_t)N * sizeof(float), stream);
  edge_score_kernel<<<(E + 3) / 4, 256, 0, stream>>>(xl, xr, att2, edges, E0, E, N, ebuf, m_enc);
  edge_exp_kernel<<<(E + 255) / 256, 256, 0, stream>>>(ebuf, edges, E0, E, N, m_enc, abuf, denom);
  agg_kernel<<<N, 256, 0, stream>>>(xl, abuf, denom, off, csr, edges, E0, bias2, gout);

  // ---- layer 2 (xr only needed for rows < L) ----
  ln_gelu_kernel<__hip_bfloat16><<<N, 256, 0, stream>>>(gout, g2, b2, ab, N);
  gemm_fused_kernel<<<gblocks, 256, 0, stream>>>(ab, wt3, bl3, br3, xl, xr, panels, L);
  hipMemsetAsync(m_enc, 0, (size_t)N * sizeof(unsigned), stream);
  hipMemsetAsync(denom, 0, (size_t)N * sizeof(float), stream);
  edge_score_kernel<<<(E + 3) / 4, 256, 0, stream>>>(xl, xr, att3, edges, E0, E, L, ebuf, m_enc);
  edge_exp_kernel<<<(E + 255) / 256, 256, 0, stream>>>(ebuf, edges, E0, E, L, m_enc, abuf, denom);
  agg_kernel<<<L, 256, 0, stream>>>(xl, abuf, denom, off, csr, edges, E0, bias3, gout);

  // final LN+GELU on the 4096 output rows, straight into d_out
  ln_gelu_kernel<float><<<L, 256, 0, stream>>>(gout, g3, b3, out_f + in_sizes[0], L);
}

// Round 4
// 749.519 us; speedup vs baseline: 3.9127x; 1.0654x over previous
//
#include <hip/hip_runtime.h>
#include <hip/hip_bf16.h>
#include <math.h>

#define H 768
#define BM 128

typedef __attribute__((ext_vector_type(4))) float f32x4;
typedef __attribute__((ext_vector_type(8))) short bf16x8;

__device__ __forceinline__ float bf2f(unsigned u16v){
  return __uint_as_float((u16v & 0xffffu) << 16);
}
__device__ __forceinline__ float gelu_exact(float x){
  return 0.5f * x * (1.0f + erff(x * 0.70710678118654752f));
}
__device__ __forceinline__ unsigned enc_f(float f){
  unsigned u = __float_as_uint(f);
  return (u & 0x80000000u) ? ~u : (u | 0x80000000u);
}
__device__ __forceinline__ float dec_f(unsigned v){
  unsigned u = (v & 0x80000000u) ? (v ^ 0x80000000u) : ~v;
  return __uint_as_float(u);
}
__device__ __forceinline__ void gload16(const void* g, void* l){
  __builtin_amdgcn_global_load_lds(
      (const __attribute__((address_space(1))) unsigned int*)g,
      (__attribute__((address_space(3))) unsigned int*)l,
      16, 0, 0);
}

// ---------------- LayerNorm + exact GELU: one block (256 thr) per row ----------------
template<typename OutT>
__global__ __launch_bounds__(256) void ln_gelu_kernel(
    const float* __restrict__ in, const float* __restrict__ g,
    const float* __restrict__ b, OutT* __restrict__ out, int rows){
  int row = blockIdx.x;
  if (row >= rows) return;
  int tid = threadIdx.x;
  const float* rp = in + (size_t)row * H;
  float v0 = rp[tid], v1 = rp[tid + 256], v2 = rp[tid + 512];
  __shared__ float red[4];
  int lane = tid & 63, wid = tid >> 6;
  float s = v0 + v1 + v2;
  for (int o = 32; o; o >>= 1) s += __shfl_down(s, o);
  if (lane == 0) red[wid] = s;
  __syncthreads();
  float mean = (red[0] + red[1] + red[2] + red[3]) * (1.0f / H);
  __syncthreads();
  float d0 = v0 - mean, d1 = v1 - mean, d2 = v2 - mean;
  s = d0*d0 + d1*d1 + d2*d2;
  for (int o = 32; o; o >>= 1) s += __shfl_down(s, o);
  if (lane == 0) red[wid] = s;
  __syncthreads();
  float var = (red[0] + red[1] + red[2] + red[3]) * (1.0f / H);
  float rstd = rsqrtf(var + 1e-5f);
  OutT* op = out + (size_t)row * H;
  float y0 = gelu_exact(d0 * rstd * g[tid]       + b[tid]);
  float y1 = gelu_exact(d1 * rstd * g[tid + 256] + b[tid + 256]);
  float y2 = gelu_exact(d2 * rstd * g[tid + 512] + b[tid + 512]);
  if constexpr (sizeof(OutT) == 2){
    op[tid]       = __float2bfloat16(y0);
    op[tid + 256] = __float2bfloat16(y1);
    op[tid + 512] = __float2bfloat16(y2);
  } else {
    op[tid]       = y0;
    op[tid + 256] = y1;
    op[tid + 512] = y2;
  }
}

// ---------------- weight transpose + f32->bf16: WT[n][k] = W[k][n] ----------------
__global__ __launch_bounds__(256) void wt_bf16_kernel(
    const float* __restrict__ W, __hip_bfloat16* __restrict__ WT){
  __shared__ float tile[32][33];
  int k0 = blockIdx.x * 32, n0 = blockIdx.y * 32;
  int tx = threadIdx.x & 31, ty = threadIdx.x >> 5;   // 32 x 8
#pragma unroll
  for (int i = 0; i < 32; i += 8)
    tile[ty + i][tx] = W[(size_t)(k0 + ty + i) * H + n0 + tx];
  __syncthreads();
#pragma unroll
  for (int i = 0; i < 32; i += 8)
    WT[(size_t)(n0 + ty + i) * H + k0 + tx] = __float2bfloat16(tile[tx][ty + i]);
}

// ---------------- fused bf16 MFMA GEMM ----------------
// [Cl | Cr] = A[panels*128,768] @ WT[1536,768]^T (+bias).
// 128x128 tile, BK=32, 3-buffer pipeline with counted vmcnt (no full drains),
// conflict-free XOR swizzle (slot ^= (row>>1)&3, both sides), XCD panel swizzle,
// LDS-staged coalesced C write. 48KB LDS -> 3 blocks/CU.
__global__ __launch_bounds__(256, 3) void gemm_fused_kernel(
    const __hip_bfloat16* __restrict__ A,
    const __hip_bfloat16* __restrict__ WT,
    const float* __restrict__ bl, const float* __restrict__ br,
    __hip_bfloat16* __restrict__ Cl, __hip_bfloat16* __restrict__ Cr,
    int panels, int Mr){
  __shared__ char smem[49152];          // 3 x (As 8KB | Bs 8KB)

  int wgid = blockIdx.x;
  int xcd = wgid & 7, j = wgid >> 3;
  int panel = xcd * (panels >> 3) + j / 12;
  int colblk = j % 12;
  int row0 = panel * BM;
  const bool is_r = colblk >= 6;
  if (is_r && row0 >= Mr) return;

  const int t = threadIdx.x;
  const int sr = t >> 2;                               // staging row 0..63
  const int scs = (((t & 3) ^ ((sr >> 1) & 3)) * 8);   // pre-swizzled global col
  const int t16 = t * 16;                              // linear LDS byte slot
  const __hip_bfloat16* pa0 = A + (size_t)(row0 + sr) * H + scs;
  const __hip_bfloat16* pa1 = pa0 + (size_t)64 * H;
  const __hip_bfloat16* pb0 = WT + (size_t)(colblk * 128 + sr) * H + scs;
  const __hip_bfloat16* pb1 = pb0 + (size_t)64 * H;

  const int l = t & 63, w = t >> 6;
  const int wm = (w >> 1) * 64, wn = (w & 1) * 64;
  const int r0 = l & 15;
  const int kcs2 = (((l >> 4) ^ ((r0 >> 1) & 3)) * 16); // swizzled frag byte col

  f32x4 acc[4][4];
#pragma unroll
  for (int m = 0; m < 4; m++)
#pragma unroll
    for (int n = 0; n < 4; n++) acc[m][n] = (f32x4){0.f, 0.f, 0.f, 0.f};

#define STAGE(kt, b) do{                                   \
    int _k0 = (kt) * 32;                                   \
    char* _bs = smem + (b) * 16384;                        \
    gload16(pa0 + _k0, _bs + t16);                         \
    gload16(pa1 + _k0, _bs + 4096 + t16);                  \
    gload16(pb0 + _k0, _bs + 8192 + t16);                  \
    gload16(pb1 + _k0, _bs + 12288 + t16);                 \
  }while(0)

  STAGE(0, 0);
  STAGE(1, 1);

  for (int kt = 0; kt < 24; kt++){
    if (kt < 23) asm volatile("s_waitcnt vmcnt(4)" ::: "memory");
    else         asm volatile("s_waitcnt vmcnt(0)" ::: "memory");
    __builtin_amdgcn_s_barrier();
    __builtin_amdgcn_sched_barrier(0);
    if (kt + 2 < 24) STAGE(kt + 2, (kt + 2) % 3);
    const char* base = smem + (kt % 3) * 16384;
    bf16x8 af[4], bfr[4];
#pragma unroll
    for (int m = 0; m < 4; m++)
      af[m]  = *(const bf16x8*)(base + (wm + m * 16 + r0) * 64 + kcs2);
#pragma unroll
    for (int n = 0; n < 4; n++)
      bfr[n] = *(const bf16x8*)(base + 8192 + (wn + n * 16 + r0) * 64 + kcs2);
#pragma unroll
    for (int m = 0; m < 4; m++)
#pragma unroll
      for (int n = 0; n < 4; n++)
        acc[m][n] = __builtin_amdgcn_mfma_f32_16x16x32_bf16(af[m], bfr[n], acc[m][n], 0, 0, 0);
  }
#undef STAGE

  // epilogue: stage C tile in LDS (XOR layout on 32B blocks), 16B coalesced stores
  __syncthreads();
  const int rgrp = (l >> 4) * 4;
  const float* bp = is_r ? br : bl;
  const int cb = (is_r ? colblk - 6 : colblk) * 128;
#pragma unroll
  for (int n = 0; n < 4; n++){
    int lc = wn + n * 16 + r0;
    float bb = bp[cb + lc];
#pragma unroll
    for (int m = 0; m < 4; m++){
#pragma unroll
      for (int jj = 0; jj < 4; jj++){
        int lr = wm + m * 16 + rgrp + jj;
        int byte = lr * 256 + ((lc * 2) ^ (((lr >> 2) & 3) << 5));
        *(__hip_bfloat16*)(smem + byte) = __float2bfloat16(acc[m][n][jj] + bb);
      }
    }
  }
  __syncthreads();
  __hip_bfloat16* C = is_r ? Cr : Cl;
#pragma unroll
  for (int p = 0; p < 8; p++){
    int ba = p * 4096 + t16;
    int lr = ba >> 8, inner = ba & 255;
    uint4 v = *(const uint4*)(smem + lr * 256 + (inner ^ (((lr >> 2) & 3) << 5)));
    *(uint4*)(C + (size_t)(row0 + lr) * H + cb + (inner >> 1)) = v;
  }
}

// ---------------- edge helpers ----------------
__device__ __forceinline__ int e_src(const int* ep, int E0, int k){
  return (k < E0) ? ep[k] : (k - E0);
}
__device__ __forceinline__ int e_dst(const int* ep, int E0, int k){
  return (k < E0) ? ep[E0 + k] : (k - E0);
}

// wave per edge: e = leaky_relu(xl[src]+xr[dst]) . att ; atomic segment max
__global__ __launch_bounds__(256) void edge_score_kernel(
    const __hip_bfloat16* __restrict__ xl, const __hip_bfloat16* __restrict__ xr,
    const float* __restrict__ att, const int* __restrict__ ep,
    int E0, int E, int limit, float* __restrict__ e_out,
    unsigned* __restrict__ m_enc){
  int k = blockIdx.x * 4 + (threadIdx.x >> 6);
  if (k >= E) return;
  int d = e_dst(ep, E0, k);
  if (d >= limit) return;
  int s = e_src(ep, E0, k);
  int lane = threadIdx.x & 63;
  const unsigned* pl = (const unsigned*)(xl + (size_t)s * H);
  const unsigned* pr = (const unsigned*)(xr + (size_t)d * H);
  float sum = 0.f;
#pragma unroll
  for (int i = 0; i < 3; i++){
    int h2 = lane * 2 + i * 128;
    uint2 vl = *(const uint2*)&pl[h2];
    uint2 vr = *(const uint2*)&pr[h2];
    float4 av = *(const float4*)&att[h2 * 2];
    float v;
    v = bf2f(vl.x) + bf2f(vr.x);             v = v > 0.f ? v : 0.2f * v; sum += v * av.x;
    v = bf2f(vl.x >> 16) + bf2f(vr.x >> 16); v = v > 0.f ? v : 0.2f * v; sum += v * av.y;
    v = bf2f(vl.y) + bf2f(vr.y);             v = v > 0.f ? v : 0.2f * v; sum += v * av.z;
    v = bf2f(vl.y >> 16) + bf2f(vr.y >> 16); v = v > 0.f ? v : 0.2f * v; sum += v * av.w;
  }
  for (int o = 32; o; o >>= 1) sum += __shfl_down(sum, o);
  if (lane == 0){
    e_out[k] = sum;
    atomicMax(&m_enc[d], enc_f(sum));
  }
}

// ---------------- CSR build (by dst) ----------------
__global__ __launch_bounds__(256) void count_kernel(const int* __restrict__ ep,
                                                    int E0, int E, int* __restrict__ cnt){
  int k = blockIdx.x * 256 + threadIdx.x;
  if (k >= E) return;
  atomicAdd(&cnt[e_dst(ep, E0, k)], 1);
}

__global__ __launch_bounds__(1024) void exscan_kernel(const int* __restrict__ cnt,
                                                      int* __restrict__ off, int n){
  __shared__ int lds[1024];
  __shared__ int carry;
  int tid = threadIdx.x;
  if (tid == 0) carry = 0;
  __syncthreads();
  for (int base = 0; base < n; base += 1024){
    int v = (base + tid < n) ? cnt[base + tid] : 0;
    lds[tid] = v;
    __syncthreads();
    for (int o = 1; o < 1024; o <<= 1){
      int tv = (tid >= o) ? lds[tid - o] : 0;
      __syncthreads();
      lds[tid] += tv;
      __syncthreads();
    }
    int inc = lds[tid];
    int c = carry;
    if (base + tid < n) off[base + tid] = c + inc - v;
    __syncthreads();
    if (tid == 1023) carry = c + lds[1023];
    __syncthreads();
  }
  if (tid == 0) off[n] = carry;
}

__global__ __launch_bounds__(256) void copy_int_kernel(const int* __restrict__ s,
                                                       int* __restrict__ d, int n){
  int i = blockIdx.x * 256 + threadIdx.x;
  if (i < n) d[i] = s[i];
}

__global__ __launch_bounds__(256) void fill_kernel(const int* __restrict__ ep, int E0, int E,
                                                   int* __restrict__ cur, int* __restrict__ csr){
  int k = blockIdx.x * 256 + threadIdx.x;
  if (k >= E) return;
  int d = e_dst(ep, E0, k);
  int pos = atomicAdd(&cur[d], 1);
  csr[pos] = k;
}

// ---------------- aggregation (fused softmax-exp + weighted sum): block per dst ----------------
__global__ __launch_bounds__(256) void agg_kernel(
    const __hip_bfloat16* __restrict__ xl, const float* __restrict__ e,
    const unsigned* __restrict__ m_enc, const int* __restrict__ off,
    const int* __restrict__ csr, const int* __restrict__ ep, int E0,
    const float* __restrict__ bias, float* __restrict__ out){
  int d = blockIdx.x;
  int tid = threadIdx.x;
  int j0 = off[d], j1 = off[d + 1];
  float m = dec_f(m_enc[d]);
  float den = 0.f, acc0 = 0.f, acc1 = 0.f, acc2 = 0.f;
  for (int j = j0; j < j1; j++){
    int k = csr[j];
    int s = e_src(ep, E0, k);
    float wgt = expf(e[k] - m);
    den += wgt;
    const unsigned short* p = (const unsigned short*)(xl + (size_t)s * H);
    acc0 += wgt * bf2f(p[tid]);
    acc1 += wgt * bf2f(p[tid + 256]);
    acc2 += wgt * bf2f(p[tid + 512]);
  }
  float inv = 1.0f / den;
  float* op = out + (size_t)d * H;
  op[tid]       = acc0 * inv + bias[tid];
  op[tid + 256] = acc1 * inv + bias[tid + 256];
  op[tid + 512] = acc2 * inv + bias[tid + 512];
}

extern "C" void kernel_launch(void* const* d_in, const int* in_sizes, int n_in,
                              void* d_out, int out_size, void* d_ws, size_t ws_size,
                              hipStream_t stream){
  const float* emb   = (const float*)d_in[0];
  const float* feats = (const float*)d_in[1];
  const int*   edges = (const int*)d_in[2];
  const float* Wl2 = (const float*)d_in[4],  *bl2 = (const float*)d_in[5];
  const float* Wr2 = (const float*)d_in[6],  *br2 = (const float*)d_in[7];
  const float* att2= (const float*)d_in[8],  *bias2=(const float*)d_in[9];
  const float* Wl3 = (const float*)d_in[10], *bl3 = (const float*)d_in[11];
  const float* Wr3 = (const float*)d_in[12], *br3 = (const float*)d_in[13];
  const float* att3= (const float*)d_in[14], *bias3=(const float*)d_in[15];
  const float* g1 = (const float*)d_in[16], *b1 = (const float*)d_in[17];
  const float* g2 = (const float*)d_in[18], *b2 = (const float*)d_in[19];
  const float* g3 = (const float*)d_in[20], *b3 = (const float*)d_in[21];

  const int N  = in_sizes[1] / H;             // 50000
  const int E0 = in_sizes[2] / 2;             // 100000
  const int E  = E0 + N;                      // 150000
  const int L  = 4096;                        // labels_size
  const int panels = ((N + BM - 1) / BM + 7) & ~7;   // 392 (multiple of 8)
  const int Mpad = panels * BM;                       // 50176

  __hip_bfloat16* ab  = (__hip_bfloat16*)d_ws;          // [Mpad][H] GEMM input
  __hip_bfloat16* xl  = ab + (size_t)Mpad * H;          // [Mpad][H]
  __hip_bfloat16* xr  = xl + (size_t)Mpad * H;          // [Mpad][H]
  __hip_bfloat16* wt2 = xr + (size_t)Mpad * H;          // [1536][H]
  __hip_bfloat16* wt3 = wt2 + (size_t)2 * H * H;        // [1536][H]
  float* gout  = (float*)(wt3 + (size_t)2 * H * H);     // [N][H] agg output
  float* ebuf  = gout + (size_t)N * H;
  unsigned* m_enc = (unsigned*)(ebuf + E);
  int* cnt = (int*)(m_enc + N);
  int* off = cnt + N;
  int* cur = off + N + 1;
  int* csr = cur + N;

  float* out_f = (float*)d_out;

  // output 0: passthrough copy of input_embeddings
  hipMemcpyAsync(out_f, emb, (size_t)in_sizes[0] * sizeof(float),
                 hipMemcpyDeviceToDevice, stream);

  // CSR by dst (shared by both layers)
  hipMemsetAsync(cnt, 0, (size_t)N * sizeof(int), stream);
  count_kernel<<<(E + 255) / 256, 256, 0, stream>>>(edges, E0, E, cnt);
  exscan_kernel<<<1, 1024, 0, stream>>>(cnt, off, N);
  copy_int_kernel<<<(N + 255) / 256, 256, 0, stream>>>(off, cur, N);
  fill_kernel<<<(E + 255) / 256, 256, 0, stream>>>(edges, E0, E, cur, csr);

  // weights -> bf16 transposed, concatenated [Wl^T ; Wr^T]
  dim3 wgrid(H / 32, H / 32);
  wt_bf16_kernel<<<wgrid, 256, 0, stream>>>(Wl2, wt2);
  wt_bf16_kernel<<<wgrid, 256, 0, stream>>>(Wr2, wt2 + (size_t)H * H);
  wt_bf16_kernel<<<wgrid, 256, 0, stream>>>(Wl3, wt3);
  wt_bf16_kernel<<<wgrid, 256, 0, stream>>>(Wr3, wt3 + (size_t)H * H);

  const int gblocks = panels * 12;

  // ---- layer 1 (full N) ----
  ln_gelu_kernel<__hip_bfloat16><<<N, 256, 0, stream>>>(feats, g1, b1, ab, N);
  gemm_fused_kernel<<<gblocks, 256, 0, stream>>>(ab, wt2, bl2, br2, xl, xr, panels, Mpad);
  hipMemsetAsync(m_enc, 0, (size_t)N * sizeof(unsigned), stream);
  edge_score_kernel<<<(E + 3) / 4, 256, 0, stream>>>(xl, xr, att2, edges, E0, E, N, ebuf, m_enc);
  agg_kernel<<<N, 256, 0, stream>>>(xl, ebuf, m_enc, off, csr, edges, E0, bias2, gout);

  // ---- layer 2 (xr only needed for rows < L) ----
  ln_gelu_kernel<__hip_bfloat16><<<N, 256, 0, stream>>>(gout, g2, b2, ab, N);
  gemm_fused_kernel<<<gblocks, 256, 0, stream>>>(ab, wt3, bl3, br3, xl, xr, panels, L);
  hipMemsetAsync(m_enc, 0, (size_t)N * sizeof(unsigned), stream);
  edge_score_kernel<<<(E + 3) / 4, 256, 0, stream>>>(xl, xr, att3, edges, E0, E, L, ebuf, m_enc);
  agg_kernel<<<L, 256, 0, stream>>>(xl, ebuf, m_enc, off, csr, edges, E0, bias3, gout);

  // final LN+GELU on the 4096 output rows, straight into d_out
  ln_gelu_kernel<float><<<L, 256, 0, stream>>>(gout, g3, b3, out_f + in_sizes[0], L);
}

// Round 5
// 470.598 us; speedup vs baseline: 6.2317x; 1.5927x over previous
//
#include <hip/hip_runtime.h>
#include <hip/hip_bf16.h>
#include <math.h>

#define H 768
#define BM 128

typedef __attribute__((ext_vector_type(4))) float f32x4;
typedef __attribute__((ext_vector_type(8))) short bf16x8;

__device__ __forceinline__ float bf2f(unsigned u16v){
  return __uint_as_float((u16v & 0xffffu) << 16);
}
__device__ __forceinline__ unsigned f2bf2(float a, float b){
  __hip_bfloat16 ha = __float2bfloat16(a), hb = __float2bfloat16(b);
  return (unsigned)*(unsigned short*)&ha | ((unsigned)*(unsigned short*)&hb << 16);
}
__device__ __forceinline__ float gelu_exact(float x){
  return 0.5f * x * (1.0f + erff(x * 0.70710678118654752f));
}
__device__ __forceinline__ void gload16(const void* g, void* l){
  __builtin_amdgcn_global_load_lds(
      (const __attribute__((address_space(1))) unsigned int*)g,
      (__attribute__((address_space(3))) unsigned int*)l,
      16, 0, 0);
}
__device__ __forceinline__ float wave_sum(float p){
#pragma unroll
  for (int o = 32; o; o >>= 1) p += __shfl_xor(p, o);
  return p;
}

// ---------------- LayerNorm + exact GELU: one WAVE per row, f32 in, bf16 out ----------------
__global__ __launch_bounds__(256) void lnw_kernel(
    const float* __restrict__ in, const float* __restrict__ g,
    const float* __restrict__ b, __hip_bfloat16* __restrict__ out, int rows){
  int row = blockIdx.x * 4 + (threadIdx.x >> 6);
  if (row >= rows) return;
  int lane = threadIdx.x & 63;
  const float* rp = in + (size_t)row * H;
  float v[12];
#pragma unroll
  for (int i = 0; i < 3; i++){
    float4 t = *(const float4*)&rp[(lane + i * 64) * 4];
    v[i*4+0] = t.x; v[i*4+1] = t.y; v[i*4+2] = t.z; v[i*4+3] = t.w;
  }
  float s = 0.f;
#pragma unroll
  for (int t = 0; t < 12; t++) s += v[t];
  float mean = wave_sum(s) * (1.0f / H);
  float s2 = 0.f;
#pragma unroll
  for (int t = 0; t < 12; t++){ float d = v[t] - mean; s2 += d * d; }
  float rstd = rsqrtf(wave_sum(s2) * (1.0f / H) + 1e-5f);
  unsigned* op = (unsigned*)(out + (size_t)row * H);
#pragma unroll
  for (int i = 0; i < 3; i++){
    float4 gv = *(const float4*)&g[(lane + i * 64) * 4];
    float4 bv = *(const float4*)&b[(lane + i * 64) * 4];
    float z0 = gelu_exact((v[i*4+0] - mean) * rstd * gv.x + bv.x);
    float z1 = gelu_exact((v[i*4+1] - mean) * rstd * gv.y + bv.y);
    float z2 = gelu_exact((v[i*4+2] - mean) * rstd * gv.z + bv.z);
    float z3 = gelu_exact((v[i*4+3] - mean) * rstd * gv.w + bv.w);
    uint2 pk; pk.x = f2bf2(z0, z1); pk.y = f2bf2(z2, z3);
    *(uint2*)&op[lane * 2 + i * 128] = pk;
  }
}

// ---------------- weight transpose + f32->bf16: WT[n][k] = W[k][n] ----------------
__global__ __launch_bounds__(256) void wt_bf16_kernel(
    const float* __restrict__ W, __hip_bfloat16* __restrict__ WT){
  __shared__ float tile[32][33];
  int k0 = blockIdx.x * 32, n0 = blockIdx.y * 32;
  int tx = threadIdx.x & 31, ty = threadIdx.x >> 5;   // 32 x 8
#pragma unroll
  for (int i = 0; i < 32; i += 8)
    tile[ty + i][tx] = W[(size_t)(k0 + ty + i) * H + n0 + tx];
  __syncthreads();
#pragma unroll
  for (int i = 0; i < 32; i += 8)
    WT[(size_t)(n0 + ty + i) * H + k0 + tx] = __float2bfloat16(tile[tx][ty + i]);
}

// ---------------- fused bf16 MFMA GEMM (validated round-4 structure) ----------------
__global__ __launch_bounds__(256, 3) void gemm_fused_kernel(
    const __hip_bfloat16* __restrict__ A,
    const __hip_bfloat16* __restrict__ WT,
    const float* __restrict__ bl, const float* __restrict__ br,
    __hip_bfloat16* __restrict__ Cl, __hip_bfloat16* __restrict__ Cr,
    int panels, int Mr){
  __shared__ char smem[49152];          // 3 x (As 8KB | Bs 8KB)

  int wgid = blockIdx.x;
  int xcd = wgid & 7, j = wgid >> 3;
  int panel = xcd * (panels >> 3) + j / 12;
  int colblk = j % 12;
  int row0 = panel * BM;
  const bool is_r = colblk >= 6;
  if (is_r && row0 >= Mr) return;

  const int t = threadIdx.x;
  const int sr = t >> 2;                               // staging row 0..63
  const int scs = (((t & 3) ^ ((sr >> 1) & 3)) * 8);   // pre-swizzled global col
  const int t16 = t * 16;                              // linear LDS byte slot
  const __hip_bfloat16* pa0 = A + (size_t)(row0 + sr) * H + scs;
  const __hip_bfloat16* pa1 = pa0 + (size_t)64 * H;
  const __hip_bfloat16* pb0 = WT + (size_t)(colblk * 128 + sr) * H + scs;
  const __hip_bfloat16* pb1 = pb0 + (size_t)64 * H;

  const int l = t & 63, w = t >> 6;
  const int wm = (w >> 1) * 64, wn = (w & 1) * 64;
  const int r0 = l & 15;
  const int kcs2 = (((l >> 4) ^ ((r0 >> 1) & 3)) * 16); // swizzled frag byte col

  f32x4 acc[4][4];
#pragma unroll
  for (int m = 0; m < 4; m++)
#pragma unroll
    for (int n = 0; n < 4; n++) acc[m][n] = (f32x4){0.f, 0.f, 0.f, 0.f};

#define STAGE(kt, b) do{                                   \
    int _k0 = (kt) * 32;                                   \
    char* _bs = smem + (b) * 16384;                        \
    gload16(pa0 + _k0, _bs + t16);                         \
    gload16(pa1 + _k0, _bs + 4096 + t16);                  \
    gload16(pb0 + _k0, _bs + 8192 + t16);                  \
    gload16(pb1 + _k0, _bs + 12288 + t16);                 \
  }while(0)

  STAGE(0, 0);
  STAGE(1, 1);

  for (int kt = 0; kt < 24; kt++){
    if (kt < 23) asm volatile("s_waitcnt vmcnt(4)" ::: "memory");
    else         asm volatile("s_waitcnt vmcnt(0)" ::: "memory");
    __builtin_amdgcn_s_barrier();
    __builtin_amdgcn_sched_barrier(0);
    if (kt + 2 < 24) STAGE(kt + 2, (kt + 2) % 3);
    const char* base = smem + (kt % 3) * 16384;
    bf16x8 af[4], bfr[4];
#pragma unroll
    for (int m = 0; m < 4; m++)
      af[m]  = *(const bf16x8*)(base + (wm + m * 16 + r0) * 64 + kcs2);
#pragma unroll
    for (int n = 0; n < 4; n++)
      bfr[n] = *(const bf16x8*)(base + 8192 + (wn + n * 16 + r0) * 64 + kcs2);
#pragma unroll
    for (int m = 0; m < 4; m++)
#pragma unroll
      for (int n = 0; n < 4; n++)
        acc[m][n] = __builtin_amdgcn_mfma_f32_16x16x32_bf16(af[m], bfr[n], acc[m][n], 0, 0, 0);
  }
#undef STAGE

  // epilogue: stage C tile in LDS (XOR layout on 32B blocks), 16B coalesced stores
  __syncthreads();
  const int rgrp = (l >> 4) * 4;
  const float* bp = is_r ? br : bl;
  const int cb = (is_r ? colblk - 6 : colblk) * 128;
#pragma unroll
  for (int n = 0; n < 4; n++){
    int lc = wn + n * 16 + r0;
    float bb = bp[cb + lc];
#pragma unroll
    for (int m = 0; m < 4; m++){
#pragma unroll
      for (int jj = 0; jj < 4; jj++){
        int lr = wm + m * 16 + rgrp + jj;
        int byte = lr * 256 + ((lc * 2) ^ (((lr >> 2) & 3) << 5));
        *(__hip_bfloat16*)(smem + byte) = __float2bfloat16(acc[m][n][jj] + bb);
      }
    }
  }
  __syncthreads();
  __hip_bfloat16* C = is_r ? Cr : Cl;
#pragma unroll
  for (int p = 0; p < 8; p++){
    int ba = p * 4096 + t16;
    int lr = ba >> 8, inner = ba & 255;
    uint4 v = *(const uint4*)(smem + lr * 256 + (inner ^ (((lr >> 2) & 3) << 5)));
    *(uint4*)(C + (size_t)(row0 + lr) * H + cb + (inner >> 1)) = v;
  }
}

// ---------------- edge helpers ----------------
__device__ __forceinline__ int e_src(const int* ep, int E0, int k){
  return (k < E0) ? ep[k] : (k - E0);
}
__device__ __forceinline__ int e_dst(const int* ep, int E0, int k){
  return (k < E0) ? ep[E0 + k] : (k - E0);
}

// ---------------- CSR build (by dst): count + hierarchical scan + fill ----------------
__global__ __launch_bounds__(256) void count_kernel(const int* __restrict__ ep,
                                                    int E0, int E, int* __restrict__ cnt){
  int k = blockIdx.x * 256 + threadIdx.x;
  if (k >= E) return;
  atomicAdd(&cnt[e_dst(ep, E0, k)], 1);
}

__global__ __launch_bounds__(1024) void scan1_kernel(const int* __restrict__ cnt,
                                                     int* __restrict__ off,
                                                     int* __restrict__ sums, int n){
  __shared__ int lds[1024];
  int tid = threadIdx.x;
  int gi = blockIdx.x * 1024 + tid;
  int v = (gi < n) ? cnt[gi] : 0;
  lds[tid] = v;
  __syncthreads();
  for (int o = 1; o < 1024; o <<= 1){
    int tv = (tid >= o) ? lds[tid - o] : 0;
    __syncthreads();
    lds[tid] += tv;
    __syncthreads();
  }
  if (gi < n) off[gi] = lds[tid] - v;          // exclusive within chunk
  if (tid == 1023) sums[blockIdx.x] = lds[1023];
}

__global__ void scan2_kernel(int* __restrict__ sums, int* __restrict__ off,
                             int nb, int n){
  int lane = threadIdx.x;                      // single wave of 64, nb <= 64
  int v = (lane < nb) ? sums[lane] : 0;
  int incl = v;
#pragma unroll
  for (int o = 1; o < 64; o <<= 1){
    int t = __shfl_up(incl, o);
    if (lane >= o) incl += t;
  }
  if (lane < nb) sums[lane] = incl - v;        // exclusive block offsets
  if (lane == nb - 1) off[n] = incl;           // grand total
}

__global__ __launch_bounds__(1024) void scan3_kernel(int* __restrict__ off,
                                                     int* __restrict__ cur,
                                                     const int* __restrict__ sums, int n){
  int gi = blockIdx.x * 1024 + threadIdx.x;
  if (gi < n){
    int v = off[gi] + sums[blockIdx.x];
    off[gi] = v;
    cur[gi] = v;
  }
}

__global__ __launch_bounds__(256) void fill_kernel(const int* __restrict__ ep, int E0, int E,
                                                   int* __restrict__ cur, int* __restrict__ csr){
  int k = blockIdx.x * 256 + threadIdx.x;
  if (k >= E) return;
  int d = e_dst(ep, E0, k);
  int pos = atomicAdd(&cur[d], 1);
  csr[pos] = k;
}

// ---------------- fused GAT attend+aggregate+LN+GELU: one WAVE per dst ----------------
// Online softmax over the dst's CSR edge list; xl[src] gathered ONCE for both
// score and weighted accumulation; LN+GELU epilogue in-wave; no atomics/barriers.
template<typename OutT>
__global__ __launch_bounds__(256) void agat_kernel(
    const __hip_bfloat16* __restrict__ xl, const __hip_bfloat16* __restrict__ xr,
    const float* __restrict__ att, const int* __restrict__ off,
    const int* __restrict__ csr, const int* __restrict__ ep, int E0,
    const float* __restrict__ bias, const float* __restrict__ g,
    const float* __restrict__ b, OutT* __restrict__ out, int ndst){
  int d = blockIdx.x * 4 + (threadIdx.x >> 6);
  if (d >= ndst) return;
  int lane = threadIdx.x & 63;
  float xrv[12], attv[12];
  const unsigned* pr = (const unsigned*)(xr + (size_t)d * H);
#pragma unroll
  for (int i = 0; i < 3; i++){
    uint2 vr = *(const uint2*)&pr[lane * 2 + i * 128];
    float4 av = *(const float4*)&att[(lane + i * 64) * 4];
    xrv[i*4+0] = bf2f(vr.x); xrv[i*4+1] = bf2f(vr.x >> 16);
    xrv[i*4+2] = bf2f(vr.y); xrv[i*4+3] = bf2f(vr.y >> 16);
    attv[i*4+0] = av.x; attv[i*4+1] = av.y; attv[i*4+2] = av.z; attv[i*4+3] = av.w;
  }
  float m = -INFINITY, den = 0.f, acc[12];
#pragma unroll
  for (int t = 0; t < 12; t++) acc[t] = 0.f;
  int j0 = off[d], j1 = off[d + 1];
  for (int j = j0; j < j1; j++){
    int k = csr[j], s = e_src(ep, E0, k);
    const unsigned* pl = (const unsigned*)(xl + (size_t)s * H);
    float xv[12];
#pragma unroll
    for (int i = 0; i < 3; i++){
      uint2 vl = *(const uint2*)&pl[lane * 2 + i * 128];
      xv[i*4+0] = bf2f(vl.x); xv[i*4+1] = bf2f(vl.x >> 16);
      xv[i*4+2] = bf2f(vl.y); xv[i*4+3] = bf2f(vl.y >> 16);
    }
    float p = 0.f;
#pragma unroll
    for (int t = 0; t < 12; t++){
      float v = xv[t] + xrv[t];
      v = (v > 0.f) ? v : 0.2f * v;
      p += v * attv[t];
    }
    p = wave_sum(p);                      // all lanes hold edge score
    float mn = fmaxf(m, p);               // branchless online softmax
    float sc = __expf(m - mn), wgt = __expf(p - mn);
    den = den * sc + wgt;
#pragma unroll
    for (int t = 0; t < 12; t++) acc[t] = acc[t] * sc + wgt * xv[t];
    m = mn;
  }
  float inv = 1.0f / den;
  float y[12];
  float s1 = 0.f;
#pragma unroll
  for (int i = 0; i < 3; i++){
    float4 bv = *(const float4*)&bias[(lane + i * 64) * 4];
    y[i*4+0] = acc[i*4+0] * inv + bv.x;
    y[i*4+1] = acc[i*4+1] * inv + bv.y;
    y[i*4+2] = acc[i*4+2] * inv + bv.z;
    y[i*4+3] = acc[i*4+3] * inv + bv.w;
  }
#pragma unroll
  for (int t = 0; t < 12; t++) s1 += y[t];
  float mean = wave_sum(s1) * (1.0f / H);
  float s2 = 0.f;
#pragma unroll
  for (int t = 0; t < 12; t++){ float dt = y[t] - mean; s2 += dt * dt; }
  float rstd = rsqrtf(wave_sum(s2) * (1.0f / H) + 1e-5f);
  OutT* op = out + (size_t)d * H;
#pragma unroll
  for (int i = 0; i < 3; i++){
    float4 gv = *(const float4*)&g[(lane + i * 64) * 4];
    float4 bv = *(const float4*)&b[(lane + i * 64) * 4];
    float z0 = gelu_exact((y[i*4+0] - mean) * rstd * gv.x + bv.x);
    float z1 = gelu_exact((y[i*4+1] - mean) * rstd * gv.y + bv.y);
    float z2 = gelu_exact((y[i*4+2] - mean) * rstd * gv.z + bv.z);
    float z3 = gelu_exact((y[i*4+3] - mean) * rstd * gv.w + bv.w);
    if constexpr (sizeof(OutT) == 2){
      uint2 pk; pk.x = f2bf2(z0, z1); pk.y = f2bf2(z2, z3);
      *(uint2*)((unsigned*)op + lane * 2 + i * 128) = pk;
    } else {
      float4 fv; fv.x = z0; fv.y = z1; fv.z = z2; fv.w = z3;
      *(float4*)&op[(lane + i * 64) * 4] = fv;
    }
  }
}

extern "C" void kernel_launch(void* const* d_in, const int* in_sizes, int n_in,
                              void* d_out, int out_size, void* d_ws, size_t ws_size,
                              hipStream_t stream){
  const float* emb   = (const float*)d_in[0];
  const float* feats = (const float*)d_in[1];
  const int*   edges = (const int*)d_in[2];
  const float* Wl2 = (const float*)d_in[4],  *bl2 = (const float*)d_in[5];
  const float* Wr2 = (const float*)d_in[6],  *br2 = (const float*)d_in[7];
  const float* att2= (const float*)d_in[8],  *bias2=(const float*)d_in[9];
  const float* Wl3 = (const float*)d_in[10], *bl3 = (const float*)d_in[11];
  const float* Wr3 = (const float*)d_in[12], *br3 = (const float*)d_in[13];
  const float* att3= (const float*)d_in[14], *bias3=(const float*)d_in[15];
  const float* g1 = (const float*)d_in[16], *b1 = (const float*)d_in[17];
  const float* g2 = (const float*)d_in[18], *b2 = (const float*)d_in[19];
  const float* g3 = (const float*)d_in[20], *b3 = (const float*)d_in[21];

  const int N  = in_sizes[1] / H;             // 50000
  const int E0 = in_sizes[2] / 2;             // 100000
  const int E  = E0 + N;                      // 150000
  const int L  = 4096;                        // labels_size
  const int panels = ((N + BM - 1) / BM + 7) & ~7;   // 392 (multiple of 8)
  const int Mpad = panels * BM;                       // 50176
  const int nchunk = (N + 1023) / 1024;               // 49 (<= 64)

  __hip_bfloat16* ab  = (__hip_bfloat16*)d_ws;          // [Mpad][H] GEMM input
  __hip_bfloat16* xl  = ab + (size_t)Mpad * H;          // [Mpad][H]
  __hip_bfloat16* xr  = xl + (size_t)Mpad * H;          // [Mpad][H]
  __hip_bfloat16* wt2 = xr + (size_t)Mpad * H;          // [1536][H]
  __hip_bfloat16* wt3 = wt2 + (size_t)2 * H * H;        // [1536][H]
  int* cnt = (int*)(wt3 + (size_t)2 * H * H);
  int* off = cnt + N;
  int* cur = off + N + 1;
  int* csr = cur + N;
  int* sums = csr + E;

  float* out_f = (float*)d_out;

  // output 0: passthrough copy of input_embeddings
  hipMemcpyAsync(out_f, emb, (size_t)in_sizes[0] * sizeof(float),
                 hipMemcpyDeviceToDevice, stream);

  // CSR by dst (shared by both layers)
  hipMemsetAsync(cnt, 0, (size_t)N * sizeof(int), stream);
  count_kernel<<<(E + 255) / 256, 256, 0, stream>>>(edges, E0, E, cnt);
  scan1_kernel<<<nchunk, 1024, 0, stream>>>(cnt, off, sums, N);
  scan2_kernel<<<1, 64, 0, stream>>>(sums, off, nchunk, N);
  scan3_kernel<<<nchunk, 1024, 0, stream>>>(off, cur, sums, N);
  fill_kernel<<<(E + 255) / 256, 256, 0, stream>>>(edges, E0, E, cur, csr);

  // weights -> bf16 transposed, concatenated [Wl^T ; Wr^T]
  dim3 wgrid(H / 32, H / 32);
  wt_bf16_kernel<<<wgrid, 256, 0, stream>>>(Wl2, wt2);
  wt_bf16_kernel<<<wgrid, 256, 0, stream>>>(Wr2, wt2 + (size_t)H * H);
  wt_bf16_kernel<<<wgrid, 256, 0, stream>>>(Wl3, wt3);
  wt_bf16_kernel<<<wgrid, 256, 0, stream>>>(Wr3, wt3 + (size_t)H * H);

  const int gblocks = panels * 12;

  // ---- layer 1 (full N) ----
  lnw_kernel<<<(N + 3) / 4, 256, 0, stream>>>(feats, g1, b1, ab, N);
  gemm_fused_kernel<<<gblocks, 256, 0, stream>>>(ab, wt2, bl2, br2, xl, xr, panels, Mpad);
  agat_kernel<__hip_bfloat16><<<(N + 3) / 4, 256, 0, stream>>>(
      xl, xr, att2, off, csr, edges, E0, bias2, g2, b2, ab, N);

  // ---- layer 2 (xr + aggregation only needed for rows < L) ----
  gemm_fused_kernel<<<gblocks, 256, 0, stream>>>(ab, wt3, bl3, br3, xl, xr, panels, L);
  agat_kernel<float><<<(L + 3) / 4, 256, 0, stream>>>(
      xl, xr, att3, off, csr, edges, E0, bias3, g3, b3, out_f + in_sizes[0], L);
}